// Round 8
// baseline (474.306 us; speedup 1.0000x reference)
//
#include <hip/hip_runtime.h>

#define ND 64   // feature dim
#define NR 8    // num edge types
#define NBUCK 8 // dst-slice buckets (== XCD count)
#define SCAN_BLOCK 256
#define SCAN_ELEMS 1024

typedef __bf16 bf16x8 __attribute__((ext_vector_type(8)));
typedef float f32x4 __attribute__((ext_vector_type(4)));
typedef unsigned short us8 __attribute__((ext_vector_type(8)));

__device__ inline unsigned short bf16_rne(float f) {
    unsigned u = __float_as_uint(f);
    unsigned r = (u + 0x7FFFu + ((u >> 16) & 1u)) >> 16;
    return (unsigned short)r;
}
__device__ inline float bf16_to_f(unsigned short s) {
    return __uint_as_float(((unsigned)s) << 16);
}

// ---------------------------------------------------------------- zero ints
__global__ __launch_bounds__(256) void zeroi_kernel(int* __restrict__ p, int n) {
    int i = blockIdx.x * 256 + threadIdx.x;
    int stride = gridDim.x * 256;
    for (; i < n; i += stride) p[i] = 0;
}

// ---------------------------------------------------------------- scan (3 kernels)
__global__ __launch_bounds__(SCAN_BLOCK) void scan1_kernel(
    const int* __restrict__ counts, int* __restrict__ offsets,
    int* __restrict__ blockSums, int S)
{
    __shared__ int lds[SCAN_BLOCK];
    int base = blockIdx.x * SCAN_ELEMS;
    int tid = threadIdx.x;
    int v[4]; int lsum = 0;
#pragma unroll
    for (int k = 0; k < 4; ++k) {
        int i = base + tid * 4 + k;
        v[k] = (i < S) ? counts[i] : 0;
        lsum += v[k];
    }
    lds[tid] = lsum;
    __syncthreads();
    int x = lsum;
    for (int off = 1; off < SCAN_BLOCK; off <<= 1) {
        int y = (tid >= off) ? lds[tid - off] : 0;
        __syncthreads();
        x += y;
        lds[tid] = x;
        __syncthreads();
    }
    int run = x - lsum;
#pragma unroll
    for (int k = 0; k < 4; ++k) {
        int i = base + tid * 4 + k;
        if (i < S) offsets[i] = run;
        run += v[k];
    }
    if (tid == SCAN_BLOCK - 1) blockSums[blockIdx.x] = x;
}

__global__ __launch_bounds__(512) void scan2_kernel(
    const int* __restrict__ blockSums, int* __restrict__ blockOffs, int nb)
{
    __shared__ int lds[512];
    int tid = threadIdx.x;
    int v = (tid < nb) ? blockSums[tid] : 0;
    lds[tid] = v;
    __syncthreads();
    int x = v;
    for (int off = 1; off < 512; off <<= 1) {
        int y = (tid >= off) ? lds[tid - off] : 0;
        __syncthreads();
        x += y;
        lds[tid] = x;
        __syncthreads();
    }
    if (tid < nb) blockOffs[tid] = x - v;
}

__global__ __launch_bounds__(SCAN_BLOCK) void scan3_kernel(
    int* __restrict__ offsets, int* __restrict__ cursor,
    const int* __restrict__ blockOffs, int S, int nEdges)
{
    int base = blockIdx.x * SCAN_ELEMS;
    int add = blockOffs[blockIdx.x];
#pragma unroll
    for (int k = 0; k < 4; ++k) {
        int i = base + threadIdx.x + k * SCAN_BLOCK;
        if (i < S) {
            int v = offsets[i] + add;
            offsets[i] = v;
            cursor[i] = v;
        }
    }
    if (blockIdx.x == 0 && threadIdx.x == 0) offsets[S] = nEdges;
}

// ---------------------------------------------------------------- phase A: bucket by dst-slice
// One pass over edges. Per 256-edge tile: LDS-count per bucket, reserve global
// space (1 atomicAdd per bucket), append (src, seg) entries. Writes land in 8
// small hot windows -> absorbed by L2, written back ~once.
__global__ __launch_bounds__(256) void bucket_kernel(
    const int* __restrict__ src, const int* __restrict__ dst,
    const int* __restrict__ typ, int* __restrict__ bcur,
    uint2* __restrict__ bbuf, int nEdges, int nNodes, int sliceSize, int bcap)
{
    __shared__ int lcnt[NBUCK];
    __shared__ int lbase[NBUCK];
    int tid = threadIdx.x;

    for (int base = blockIdx.x * 256; base < nEdges; base += gridDim.x * 256) {
        int e = base + tid;
        int b = -1; uint2 entry;
        if (e < nEdges) {
            int d = dst[e];
            b = d / sliceSize;
            entry.x = (unsigned)src[e];
            entry.y = (unsigned)(typ[e] * nNodes + d);
        }
        if (tid < NBUCK) lcnt[tid] = 0;
        __syncthreads();
        int myofs = 0;
        if (b >= 0) myofs = atomicAdd(&lcnt[b], 1);
        __syncthreads();
        if (tid < NBUCK) lbase[tid] = atomicAdd(&bcur[tid], lcnt[tid]);
        __syncthreads();
        if (b >= 0) bbuf[(long)b * bcap + lbase[b] + myofs] = entry;
        __syncthreads();
    }
}

// ---------------------------------------------------------------- phase B1: per-slice histogram
// slice = blockIdx&7 (XCD-affine). Reads only its own bucket (1.6 MB seq);
// atomics into the slice's 200 KB cnt region -> XCD-local L2.
__global__ __launch_bounds__(256) void histb_kernel(
    const uint2* __restrict__ bbuf, const int* __restrict__ bcur,
    int* __restrict__ cnt, int bcap)
{
    int slice = blockIdx.x & 7;
    int chunk = blockIdx.x >> 3;
    int nchunk = gridDim.x >> 3;
    int n = bcur[slice];
    const uint2* buf = bbuf + (long)slice * bcap;
    for (int i = chunk * 256 + threadIdx.x; i < n; i += nchunk * 256)
        atomicAdd(cnt + buf[i].y, 1);
}

// ---------------------------------------------------------------- phase B2: per-slice counting-sort scatter
// Working set per slice: bucket stream 1.6MB + perm 800KB + cursor 200KB < 4MB L2.
__global__ __launch_bounds__(256) void sortslice_kernel(
    const uint2* __restrict__ bbuf, const int* __restrict__ bcur,
    int* __restrict__ cursor, int* __restrict__ perm, int bcap)
{
    int slice = blockIdx.x & 7;
    int chunk = blockIdx.x >> 3;
    int nchunk = gridDim.x >> 3;
    int n = bcur[slice];
    const uint2* buf = bbuf + (long)slice * bcap;
    for (int i = chunk * 256 + threadIdx.x; i < n; i += nchunk * 256) {
        uint2 e = buf[i];
        int pos = atomicAdd(cursor + e.y, 1);
        perm[pos] = (int)e.x;
    }
}

// ---------------------------------------------------------------- weight convert+transpose
// wt[o][k] (bf16, [64][512]) = W[k][o]  where k = r*64+i  (W flat is [512][64])
__global__ __launch_bounds__(256) void convw_kernel(
    const float* __restrict__ W, unsigned short* __restrict__ wt)
{
    int idx = blockIdx.x * 256 + threadIdx.x;
    if (idx >= 64 * 512) return;
    int o = idx >> 9, k = idx & 511;
    wt[idx] = bf16_rne(W[(long)k * 64 + o]);
}

// ---------------------------------------------------------------- x -> bf16
__global__ __launch_bounds__(256) void convx_kernel(
    const float4* __restrict__ x, unsigned short* __restrict__ xb, int n8)
{
    int i = blockIdx.x * 256 + threadIdx.x;
    if (i >= n8) return;
    float4 v0 = x[i * 2], v1 = x[i * 2 + 1];
    us8 o;
    o[0] = bf16_rne(v0.x); o[1] = bf16_rne(v0.y);
    o[2] = bf16_rne(v0.z); o[3] = bf16_rne(v0.w);
    o[4] = bf16_rne(v1.x); o[5] = bf16_rne(v1.y);
    o[6] = bf16_rne(v1.z); o[7] = bf16_rne(v1.w);
    *(us8*)(xb + (long)i * 8) = o;
}

// ---------------------------------------------------------------- gather
// 16 lanes per segment; lane owns 4 features (ushort4 = 8 B/lane).
// 4 segments per wave, grid-stride persistent.
__global__ __launch_bounds__(256) void gather_kernel(
    const unsigned short* __restrict__ xb, const int* __restrict__ offsets,
    const int* __restrict__ perm, unsigned short* __restrict__ agbf,
    int S, int nNodes)
{
    int tid = threadIdx.x;
    int gidx = (blockIdx.x * 256 + tid) >> 4;
    int nGroups = (gridDim.x * 256) >> 4;
    int fl = tid & 15;

    for (int s = gidx; s < S; s += nGroups) {
        int beg = offsets[s], end = offsets[s + 1];
        float a0 = 0.f, a1 = 0.f, a2 = 0.f, a3 = 0.f;
        for (int p = beg; p < end; ++p) {
            int srcn = perm[p];
            ushort4 v = *(const ushort4*)(xb + (long)srcn * ND + fl * 4);
            a0 += bf16_to_f(v.x); a1 += bf16_to_f(v.y);
            a2 += bf16_to_f(v.z); a3 += bf16_to_f(v.w);
        }
        int r = s / nNodes;
        int node = s - r * nNodes;
        ushort4 o;
        o.x = bf16_rne(a0); o.y = bf16_rne(a1);
        o.z = bf16_rne(a2); o.w = bf16_rne(a3);
        *(ushort4*)(agbf + (long)node * 512 + r * ND + fl * 4) = o;
    }
}

// ---------------------------------------------------------------- MFMA einsum
// msgs[M=nodes, 64] = A[M, 512] @ Wt^T   (A = agbf, Wt = [64][512] bf16)
__global__ __launch_bounds__(256) void einsum_kernel(
    const unsigned short* __restrict__ agbf, const unsigned short* __restrict__ wt,
    float* __restrict__ msgs, int nNodes)
{
    int wid = blockIdx.x * 4 + (threadIdx.x >> 6);
    int lane = threadIdx.x & 63;
    int nbase = wid * 32;
    if (nbase >= nNodes) return;
    int r16 = lane & 15;
    int kg  = lane >> 4;

    f32x4 acc[2][4];
#pragma unroll
    for (int m = 0; m < 2; ++m)
#pragma unroll
        for (int j = 0; j < 4; ++j) acc[m][j] = (f32x4){0.f, 0.f, 0.f, 0.f};

    int n0 = nbase + r16;      if (n0 >= nNodes) n0 = nNodes - 1;
    int n1 = nbase + 16 + r16; if (n1 >= nNodes) n1 = nNodes - 1;
    const unsigned short* a0p = agbf + (long)n0 * 512 + kg * 8;
    const unsigned short* a1p = agbf + (long)n1 * 512 + kg * 8;
    const unsigned short* bp  = wt + (long)r16 * 512 + kg * 8;

#pragma unroll 4
    for (int kk = 0; kk < 16; ++kk) {
        bf16x8 a0 = *(const bf16x8*)(a0p + kk * 32);
        bf16x8 a1 = *(const bf16x8*)(a1p + kk * 32);
#pragma unroll
        for (int j = 0; j < 4; ++j) {
            bf16x8 b = *(const bf16x8*)(bp + (long)j * 16 * 512 + kk * 32);
            acc[0][j] = __builtin_amdgcn_mfma_f32_16x16x32_bf16(a0, b, acc[0][j], 0, 0, 0);
            acc[1][j] = __builtin_amdgcn_mfma_f32_16x16x32_bf16(a1, b, acc[1][j], 0, 0, 0);
        }
    }

    // C layout (verified m89): col = lane&15, row = (lane>>4)*4 + reg
#pragma unroll
    for (int m = 0; m < 2; ++m) {
#pragma unroll
        for (int reg = 0; reg < 4; ++reg) {
            int row = nbase + m * 16 + kg * 4 + reg;
            if (row < nNodes) {
#pragma unroll
                for (int j = 0; j < 4; ++j)
                    msgs[(long)row * ND + j * 16 + r16] = acc[m][j][reg];
            }
        }
    }
}

// ---------------------------------------------------------------- MLP (quad structure)
__global__ __launch_bounds__(256, 2) void mlp_kernel(
    const float* __restrict__ xin, const float* __restrict__ msgs,
    const float* __restrict__ bias, const float* __restrict__ eps,
    const float* __restrict__ mw1, const float* __restrict__ mb1,
    const float* __restrict__ mw2, const float* __restrict__ mb2,
    float* __restrict__ out, unsigned short* __restrict__ out_bf, int nNodes)
{
    __shared__ float w_lds[ND * ND];

    int tid  = threadIdx.x;
    int lane = tid & 63;
    int quad = tid & 3;
    int nl   = tid >> 2;
    int node = blockIdx.x * 64 + nl;
    bool active = node < nNodes;
    int nc = active ? node : (nNodes - 1);

    float epsv = 1.0f + eps[0];
    int obase = quad * 16;

    float h[16];
    {
        const float4* xr = (const float4*)(xin + (long)nc * ND + obase);
        const float4* mr = (const float4*)(msgs + (long)nc * ND + obase);
#pragma unroll
        for (int k = 0; k < 4; ++k) {
            float4 v = xr[k], m = mr[k];
            h[4 * k + 0] = fmaf(epsv, v.x, m.x); h[4 * k + 1] = fmaf(epsv, v.y, m.y);
            h[4 * k + 2] = fmaf(epsv, v.z, m.z); h[4 * k + 3] = fmaf(epsv, v.w, m.w);
        }
    }

    {
        const float4* wg = (const float4*)mw1 + tid * 4;
        float4* wl = (float4*)w_lds + tid * 4;
#pragma unroll
        for (int k = 0; k < 4; ++k) wl[k] = wg[k];
    }
    float t[16];
    {
        const float4* br = (const float4*)(mb1 + obase);
#pragma unroll
        for (int k = 0; k < 4; ++k) {
            float4 v = br[k];
            t[4 * k + 0] = v.x; t[4 * k + 1] = v.y;
            t[4 * k + 2] = v.z; t[4 * k + 3] = v.w;
        }
    }
    __syncthreads();
#pragma unroll
    for (int i = 0; i < ND; ++i) {
        float hi = __shfl(h[i & 15], (lane & 60) | (i >> 4));
        const float4* wr4 = (const float4*)(w_lds + i * ND + obase);
        float4 w0 = wr4[0], w1 = wr4[1], w2 = wr4[2], w3 = wr4[3];
        t[0]  = fmaf(hi, w0.x, t[0]);  t[1]  = fmaf(hi, w0.y, t[1]);
        t[2]  = fmaf(hi, w0.z, t[2]);  t[3]  = fmaf(hi, w0.w, t[3]);
        t[4]  = fmaf(hi, w1.x, t[4]);  t[5]  = fmaf(hi, w1.y, t[5]);
        t[6]  = fmaf(hi, w1.z, t[6]);  t[7]  = fmaf(hi, w1.w, t[7]);
        t[8]  = fmaf(hi, w2.x, t[8]);  t[9]  = fmaf(hi, w2.y, t[9]);
        t[10] = fmaf(hi, w2.z, t[10]); t[11] = fmaf(hi, w2.w, t[11]);
        t[12] = fmaf(hi, w3.x, t[12]); t[13] = fmaf(hi, w3.y, t[13]);
        t[14] = fmaf(hi, w3.z, t[14]); t[15] = fmaf(hi, w3.w, t[15]);
    }
#pragma unroll
    for (int j = 0; j < 16; ++j) t[j] = fmaxf(t[j], 0.f);

    __syncthreads();
    {
        const float4* wg = (const float4*)mw2 + tid * 4;
        float4* wl = (float4*)w_lds + tid * 4;
#pragma unroll
        for (int k = 0; k < 4; ++k) wl[k] = wg[k];
    }
    float o[16];
    {
        const float4* b2r = (const float4*)(mb2 + obase);
        const float4* bbr = (const float4*)(bias + obase);
#pragma unroll
        for (int k = 0; k < 4; ++k) {
            float4 v = b2r[k], u = bbr[k];
            o[4 * k + 0] = v.x + u.x; o[4 * k + 1] = v.y + u.y;
            o[4 * k + 2] = v.z + u.z; o[4 * k + 3] = v.w + u.w;
        }
    }
    __syncthreads();
#pragma unroll
    for (int i = 0; i < ND; ++i) {
        float ti = __shfl(t[i & 15], (lane & 60) | (i >> 4));
        const float4* wr4 = (const float4*)(w_lds + i * ND + obase);
        float4 w0 = wr4[0], w1 = wr4[1], w2 = wr4[2], w3 = wr4[3];
        o[0]  = fmaf(ti, w0.x, o[0]);  o[1]  = fmaf(ti, w0.y, o[1]);
        o[2]  = fmaf(ti, w0.z, o[2]);  o[3]  = fmaf(ti, w0.w, o[3]);
        o[4]  = fmaf(ti, w1.x, o[4]);  o[5]  = fmaf(ti, w1.y, o[5]);
        o[6]  = fmaf(ti, w1.z, o[6]);  o[7]  = fmaf(ti, w1.w, o[7]);
        o[8]  = fmaf(ti, w2.x, o[8]);  o[9]  = fmaf(ti, w2.y, o[9]);
        o[10] = fmaf(ti, w2.z, o[10]); o[11] = fmaf(ti, w2.w, o[11]);
        o[12] = fmaf(ti, w3.x, o[12]); o[13] = fmaf(ti, w3.y, o[13]);
        o[14] = fmaf(ti, w3.z, o[14]); o[15] = fmaf(ti, w3.w, o[15]);
    }

    if (!active) return;
    float4* outr = (float4*)(out + (long)node * ND + obase);
#pragma unroll
    for (int k = 0; k < 4; ++k)
        outr[k] = make_float4(o[4 * k + 0], o[4 * k + 1], o[4 * k + 2], o[4 * k + 3]);
    if (out_bf != nullptr) {
        us8 b0, b1;
#pragma unroll
        for (int k = 0; k < 8; ++k) { b0[k] = bf16_rne(o[k]); b1[k] = bf16_rne(o[8 + k]); }
        us8* obr = (us8*)(out_bf + (long)node * ND + obase);
        obr[0] = b0; obr[1] = b1;
    }
}

// ---------------------------------------------------------------- launch
extern "C" void kernel_launch(void* const* d_in, const int* in_sizes, int n_in,
                              void* d_out, int out_size, void* d_ws, size_t ws_size,
                              hipStream_t stream) {
    const float* x    = (const float*)d_in[0];
    const int* esrc   = (const int*)d_in[1];
    const int* edst   = (const int*)d_in[2];
    const int* etyp   = (const int*)d_in[3];

    const float* W1   = (const float*)d_in[4];
    const float* b1   = (const float*)d_in[5];
    const float* e1   = (const float*)d_in[6];
    const float* m1w1 = (const float*)d_in[7];
    const float* m1b1 = (const float*)d_in[8];
    const float* m1w2 = (const float*)d_in[9];
    const float* m1b2 = (const float*)d_in[10];

    const float* W2   = (const float*)d_in[11];
    const float* b2   = (const float*)d_in[12];
    const float* e2   = (const float*)d_in[13];
    const float* m2w1 = (const float*)d_in[14];
    const float* m2b1 = (const float*)d_in[15];
    const float* m2w2 = (const float*)d_in[16];
    const float* m2b2 = (const float*)d_in[17];

    int nNodes = in_sizes[0] / ND;   // 50000
    int nEdges = in_sizes[1];        // 1600000
    int S = NR * nNodes;             // 400000
    int nb = (S + SCAN_ELEMS - 1) / SCAN_ELEMS;
    int sliceSize = (nNodes + NBUCK - 1) / NBUCK;  // 6250
    int bcap = nEdges / NBUCK + 16384;             // per-bucket capacity

    // ---- workspace layout (8B-aligned regions first)
    unsigned short* agbf = (unsigned short*)d_ws;                 // N*512 bf16 = 51.2MB
    float* msgs   = (float*)(agbf + (long)nNodes * 512);          // N*64 f32 = 12.8MB
    unsigned short* xhbf = (unsigned short*)(msgs + (long)nNodes * ND); // N*64 bf16 = 6.4MB
    unsigned short* wt1 = xhbf + (long)nNodes * ND;               // 64*512 bf16
    unsigned short* wt2 = wt1 + 64 * 512;
    uint2* bbuf   = (uint2*)(wt2 + 64 * 512);                     // 8*bcap*8B = 13.8MB
    int* offsets  = (int*)(bbuf + (long)NBUCK * bcap);            // S+1
    int* cnt_cur  = offsets + (S + 1);                            // S (counts -> cursor)
    int* bcur     = cnt_cur + S;                                  // NBUCK (adjacent: zeroed together)
    int* blockSums = bcur + NBUCK;
    int* blockOffs = blockSums + 512;
    int* perm     = blockOffs + 512;                              // E
    float* h    = (float*)d_out;   // layer-1 fp32 h aliases d_out
    float* outp = (float*)d_out;

    int ggrid = 2048;
    int mgrid = (nNodes + 63) / 64;
    int esgrid = ((nNodes + 31) / 32 + 3) / 4;
    int n8 = nNodes * ND / 8;

    // ---- build CSR once (two-phase bucketed counting sort)
    zeroi_kernel<<<512, 256, 0, stream>>>(cnt_cur, S + NBUCK);   // counts + bucket cursors
    bucket_kernel<<<1024, 256, 0, stream>>>(esrc, edst, etyp, bcur, bbuf,
                                            nEdges, nNodes, sliceSize, bcap);
    histb_kernel<<<2048, 256, 0, stream>>>(bbuf, bcur, cnt_cur, bcap);
    scan1_kernel<<<nb, SCAN_BLOCK, 0, stream>>>(cnt_cur, offsets, blockSums, S);
    scan2_kernel<<<1, 512, 0, stream>>>(blockSums, blockOffs, nb);
    scan3_kernel<<<nb, SCAN_BLOCK, 0, stream>>>(offsets, cnt_cur, blockOffs, S, nEdges);
    sortslice_kernel<<<2048, 256, 0, stream>>>(bbuf, bcur, cnt_cur, perm, bcap);

    // ---- weight + x converts
    convw_kernel<<<128, 256, 0, stream>>>(W1, wt1);
    convw_kernel<<<128, 256, 0, stream>>>(W2, wt2);
    convx_kernel<<<(n8 + 255) / 256, 256, 0, stream>>>((const float4*)x, xhbf, n8);

    // ---- layer 1
    gather_kernel<<<ggrid, 256, 0, stream>>>(xhbf, offsets, perm, agbf, S, nNodes);
    einsum_kernel<<<esgrid, 256, 0, stream>>>(agbf, wt1, msgs, nNodes);
    mlp_kernel<<<mgrid, 256, 0, stream>>>(x, msgs, b1, e1, m1w1, m1b1, m1w2, m1b2,
                                          h, xhbf, nNodes);

    // ---- layer 2
    gather_kernel<<<ggrid, 256, 0, stream>>>(xhbf, offsets, perm, agbf, S, nNodes);
    einsum_kernel<<<esgrid, 256, 0, stream>>>(agbf, wt2, msgs, nNodes);
    mlp_kernel<<<mgrid, 256, 0, stream>>>(h, msgs, b2, e2, m2w1, m2b1, m2w2, m2b2,
                                          outp, nullptr, nNodes);
}

// Round 9
// 384.709 us; speedup vs baseline: 1.2329x; 1.2329x over previous
//
#include <hip/hip_runtime.h>

#define ND 64   // feature dim
#define NR 8    // num edge types
#define SCAN_BLOCK 256
#define SCAN_ELEMS 1024

typedef __bf16 bf16x8 __attribute__((ext_vector_type(8)));
typedef float f32x4 __attribute__((ext_vector_type(4)));
typedef unsigned short us8 __attribute__((ext_vector_type(8)));

__device__ inline unsigned short bf16_rne(float f) {
    unsigned u = __float_as_uint(f);
    unsigned r = (u + 0x7FFFu + ((u >> 16) & 1u)) >> 16;
    return (unsigned short)r;
}
__device__ inline float bf16_to_f(unsigned short s) {
    return __uint_as_float(((unsigned)s) << 16);
}

// ---------------------------------------------------------------- zero ints
__global__ __launch_bounds__(256) void zeroi_kernel(int* __restrict__ p, int n) {
    int i = blockIdx.x * 256 + threadIdx.x;
    int stride = gridDim.x * 256;
    for (; i < n; i += stride) p[i] = 0;
}

// ---------------------------------------------------------------- histogram
__global__ __launch_bounds__(256) void hist_kernel(
    const int* __restrict__ dst, const int* __restrict__ typ,
    int* __restrict__ cnt, int nEdges, int nNodes)
{
    int e = blockIdx.x * 256 + threadIdx.x;
    if (e < nEdges) atomicAdd(cnt + typ[e] * nNodes + dst[e], 1);
}

// ---------------------------------------------------------------- scan (3 kernels)
__global__ __launch_bounds__(SCAN_BLOCK) void scan1_kernel(
    const int* __restrict__ counts, int* __restrict__ offsets,
    int* __restrict__ blockSums, int S)
{
    __shared__ int lds[SCAN_BLOCK];
    int base = blockIdx.x * SCAN_ELEMS;
    int tid = threadIdx.x;
    int v[4]; int lsum = 0;
#pragma unroll
    for (int k = 0; k < 4; ++k) {
        int i = base + tid * 4 + k;
        v[k] = (i < S) ? counts[i] : 0;
        lsum += v[k];
    }
    lds[tid] = lsum;
    __syncthreads();
    int x = lsum;
    for (int off = 1; off < SCAN_BLOCK; off <<= 1) {
        int y = (tid >= off) ? lds[tid - off] : 0;
        __syncthreads();
        x += y;
        lds[tid] = x;
        __syncthreads();
    }
    int run = x - lsum;
#pragma unroll
    for (int k = 0; k < 4; ++k) {
        int i = base + tid * 4 + k;
        if (i < S) offsets[i] = run;
        run += v[k];
    }
    if (tid == SCAN_BLOCK - 1) blockSums[blockIdx.x] = x;
}

__global__ __launch_bounds__(512) void scan2_kernel(
    const int* __restrict__ blockSums, int* __restrict__ blockOffs, int nb)
{
    __shared__ int lds[512];
    int tid = threadIdx.x;
    int v = (tid < nb) ? blockSums[tid] : 0;
    lds[tid] = v;
    __syncthreads();
    int x = v;
    for (int off = 1; off < 512; off <<= 1) {
        int y = (tid >= off) ? lds[tid - off] : 0;
        __syncthreads();
        x += y;
        lds[tid] = x;
        __syncthreads();
    }
    if (tid < nb) blockOffs[tid] = x - v;
}

__global__ __launch_bounds__(SCAN_BLOCK) void scan3_kernel(
    int* __restrict__ offsets, int* __restrict__ cursor,
    const int* __restrict__ blockOffs, int S, int nEdges)
{
    int base = blockIdx.x * SCAN_ELEMS;
    int add = blockOffs[blockIdx.x];
#pragma unroll
    for (int k = 0; k < 4; ++k) {
        int i = base + threadIdx.x + k * SCAN_BLOCK;
        if (i < S) {
            int v = offsets[i] + add;
            offsets[i] = v;
            cursor[i] = v;
        }
    }
    if (blockIdx.x == 0 && threadIdx.x == 0) offsets[S] = nEdges;
}

// ---------------------------------------------------------------- permute (XCD-sliced, R7 version)
__global__ __launch_bounds__(256) void permute_kernel(
    const int* __restrict__ src, const int* __restrict__ dst,
    const int* __restrict__ typ, int* __restrict__ cursor,
    int* __restrict__ perm, int nEdges, int nNodes,
    int chunkSize, int sliceSize)
{
    int chunk = blockIdx.x >> 3;
    int slice = blockIdx.x & 7;
    int lo = slice * sliceSize;
    int hi = lo + sliceSize;
    int beg = chunk * chunkSize;
    int end = min(beg + chunkSize, nEdges);
    for (int e = beg + threadIdx.x; e < end; e += 256) {
        int d = dst[e];
        if (d >= lo && d < hi) {
            int seg = typ[e] * nNodes + d;
            int pos = atomicAdd(cursor + seg, 1);
            perm[pos] = src[e];
        }
    }
}

// ---------------------------------------------------------------- weight convert+transpose (relation W)
// wt[o][k] (bf16, [64][512]) = W[k][o]  where k = r*64+i  (W flat is [512][64])
__global__ __launch_bounds__(256) void convw_kernel(
    const float* __restrict__ W, unsigned short* __restrict__ wt)
{
    int idx = blockIdx.x * 256 + threadIdx.x;
    if (idx >= 64 * 512) return;
    int o = idx >> 9, k = idx & 511;
    wt[idx] = bf16_rne(W[(long)k * 64 + o]);
}

// ---------------------------------------------------------------- MLP weight convert+transpose (64x64)
// wmt[o][k] = m[k][o]
__global__ __launch_bounds__(256) void convm_kernel(
    const float* __restrict__ m, unsigned short* __restrict__ wmt)
{
    int idx = blockIdx.x * 256 + threadIdx.x;
    if (idx >= 64 * 64) return;
    int o = idx >> 6, k = idx & 63;
    wmt[idx] = bf16_rne(m[k * 64 + o]);
}

// ---------------------------------------------------------------- x -> bf16
__global__ __launch_bounds__(256) void convx_kernel(
    const float4* __restrict__ x, unsigned short* __restrict__ xb, int n8)
{
    int i = blockIdx.x * 256 + threadIdx.x;
    if (i >= n8) return;
    float4 v0 = x[i * 2], v1 = x[i * 2 + 1];
    us8 o;
    o[0] = bf16_rne(v0.x); o[1] = bf16_rne(v0.y);
    o[2] = bf16_rne(v0.z); o[3] = bf16_rne(v0.w);
    o[4] = bf16_rne(v1.x); o[5] = bf16_rne(v1.y);
    o[6] = bf16_rne(v1.z); o[7] = bf16_rne(v1.w);
    *(us8*)(xb + (long)i * 8) = o;
}

// ---------------------------------------------------------------- gather
// 16 lanes per segment; lane owns 4 features (ushort4 = 8 B/lane).
// 4 segments per wave, grid-stride persistent.
__global__ __launch_bounds__(256) void gather_kernel(
    const unsigned short* __restrict__ xb, const int* __restrict__ offsets,
    const int* __restrict__ perm, unsigned short* __restrict__ agbf,
    int S, int nNodes)
{
    int tid = threadIdx.x;
    int gidx = (blockIdx.x * 256 + tid) >> 4;
    int nGroups = (gridDim.x * 256) >> 4;
    int fl = tid & 15;

    for (int s = gidx; s < S; s += nGroups) {
        int beg = offsets[s], end = offsets[s + 1];
        float a0 = 0.f, a1 = 0.f, a2 = 0.f, a3 = 0.f;
        for (int p = beg; p < end; ++p) {
            int srcn = perm[p];
            ushort4 v = *(const ushort4*)(xb + (long)srcn * ND + fl * 4);
            a0 += bf16_to_f(v.x); a1 += bf16_to_f(v.y);
            a2 += bf16_to_f(v.z); a3 += bf16_to_f(v.w);
        }
        int r = s / nNodes;
        int node = s - r * nNodes;
        ushort4 o;
        o.x = bf16_rne(a0); o.y = bf16_rne(a1);
        o.z = bf16_rne(a2); o.w = bf16_rne(a3);
        *(ushort4*)(agbf + (long)node * 512 + r * ND + fl * 4) = o;
    }
}

// ---------------------------------------------------------------- MFMA einsum
// msgs[M=nodes, 64] = A[M, 512] @ Wt^T   (A = agbf, Wt = [64][512] bf16)
__global__ __launch_bounds__(256) void einsum_kernel(
    const unsigned short* __restrict__ agbf, const unsigned short* __restrict__ wt,
    float* __restrict__ msgs, int nNodes)
{
    int wid = blockIdx.x * 4 + (threadIdx.x >> 6);
    int lane = threadIdx.x & 63;
    int nbase = wid * 32;
    if (nbase >= nNodes) return;
    int r16 = lane & 15;
    int kg  = lane >> 4;

    f32x4 acc[2][4];
#pragma unroll
    for (int m = 0; m < 2; ++m)
#pragma unroll
        for (int j = 0; j < 4; ++j) acc[m][j] = (f32x4){0.f, 0.f, 0.f, 0.f};

    int n0 = nbase + r16;      if (n0 >= nNodes) n0 = nNodes - 1;
    int n1 = nbase + 16 + r16; if (n1 >= nNodes) n1 = nNodes - 1;
    const unsigned short* a0p = agbf + (long)n0 * 512 + kg * 8;
    const unsigned short* a1p = agbf + (long)n1 * 512 + kg * 8;
    const unsigned short* bp  = wt + (long)r16 * 512 + kg * 8;

#pragma unroll 4
    for (int kk = 0; kk < 16; ++kk) {
        bf16x8 a0 = *(const bf16x8*)(a0p + kk * 32);
        bf16x8 a1 = *(const bf16x8*)(a1p + kk * 32);
#pragma unroll
        for (int j = 0; j < 4; ++j) {
            bf16x8 b = *(const bf16x8*)(bp + (long)j * 16 * 512 + kk * 32);
            acc[0][j] = __builtin_amdgcn_mfma_f32_16x16x32_bf16(a0, b, acc[0][j], 0, 0, 0);
            acc[1][j] = __builtin_amdgcn_mfma_f32_16x16x32_bf16(a1, b, acc[1][j], 0, 0, 0);
        }
    }

    // C layout (verified m89): col = lane&15, row = (lane>>4)*4 + reg
#pragma unroll
    for (int m = 0; m < 2; ++m) {
#pragma unroll
        for (int reg = 0; reg < 4; ++reg) {
            int row = nbase + m * 16 + kg * 4 + reg;
            if (row < nNodes) {
#pragma unroll
                for (int j = 0; j < 4; ++j)
                    msgs[(long)row * ND + j * 16 + r16] = acc[m][j][reg];
            }
        }
    }
}

// ---------------------------------------------------------------- MFMA MLP stage A
// t[N,64] bf16 = relu( ((1+eps)*x + msgs) @ wm1t^T + mb1 )
// wm1t is [64 out][64 in] bf16. Same fragment geometry as einsum, K=64.
__global__ __launch_bounds__(256) void mlpA_kernel(
    const float* __restrict__ xin, const float* __restrict__ msgs,
    const float* __restrict__ eps, const unsigned short* __restrict__ wm1t,
    const float* __restrict__ mb1, unsigned short* __restrict__ tout, int nNodes)
{
    int wid = blockIdx.x * 4 + (threadIdx.x >> 6);
    int lane = threadIdx.x & 63;
    int nbase = wid * 32;
    if (nbase >= nNodes) return;
    int r16 = lane & 15;
    int kg  = lane >> 4;
    float epsv = 1.0f + eps[0];

    int n0 = nbase + r16;      if (n0 >= nNodes) n0 = nNodes - 1;
    int n1 = nbase + 16 + r16; if (n1 >= nNodes) n1 = nNodes - 1;

    // build A-frags a[m][kk]: h = (1+eps)*x + msgs at k = kg*8 + kk*32 + 0..7
    bf16x8 afr[2][2];
#pragma unroll
    for (int m = 0; m < 2; ++m) {
        long nrow = (m == 0) ? n0 : n1;
#pragma unroll
        for (int kk = 0; kk < 2; ++kk) {
            long base = nrow * ND + kg * 8 + kk * 32;
            float4 x0 = *(const float4*)(xin + base);
            float4 x1 = *(const float4*)(xin + base + 4);
            float4 m0 = *(const float4*)(msgs + base);
            float4 m1 = *(const float4*)(msgs + base + 4);
            us8 u;
            u[0] = bf16_rne(fmaf(epsv, x0.x, m0.x));
            u[1] = bf16_rne(fmaf(epsv, x0.y, m0.y));
            u[2] = bf16_rne(fmaf(epsv, x0.z, m0.z));
            u[3] = bf16_rne(fmaf(epsv, x0.w, m0.w));
            u[4] = bf16_rne(fmaf(epsv, x1.x, m1.x));
            u[5] = bf16_rne(fmaf(epsv, x1.y, m1.y));
            u[6] = bf16_rne(fmaf(epsv, x1.z, m1.z));
            u[7] = bf16_rne(fmaf(epsv, x1.w, m1.w));
            afr[m][kk] = __builtin_bit_cast(bf16x8, u);
        }
    }

    f32x4 acc[2][4];
#pragma unroll
    for (int m = 0; m < 2; ++m)
#pragma unroll
        for (int j = 0; j < 4; ++j) acc[m][j] = (f32x4){0.f, 0.f, 0.f, 0.f};

#pragma unroll
    for (int kk = 0; kk < 2; ++kk) {
#pragma unroll
        for (int j = 0; j < 4; ++j) {
            bf16x8 b = *(const bf16x8*)(wm1t + (long)(j * 16 + r16) * ND + kg * 8 + kk * 32);
            acc[0][j] = __builtin_amdgcn_mfma_f32_16x16x32_bf16(afr[0][kk], b, acc[0][j], 0, 0, 0);
            acc[1][j] = __builtin_amdgcn_mfma_f32_16x16x32_bf16(afr[1][kk], b, acc[1][j], 0, 0, 0);
        }
    }

#pragma unroll
    for (int m = 0; m < 2; ++m) {
#pragma unroll
        for (int reg = 0; reg < 4; ++reg) {
            int row = nbase + m * 16 + kg * 4 + reg;
            if (row < nNodes) {
#pragma unroll
                for (int j = 0; j < 4; ++j) {
                    int col = j * 16 + r16;
                    float v = acc[m][j][reg] + mb1[col];
                    v = fmaxf(v, 0.f);
                    tout[(long)row * ND + col] = bf16_rne(v);
                }
            }
        }
    }
}

// ---------------------------------------------------------------- MFMA MLP stage B
// out[N,64] f32 = t @ wm2t^T + mb2 + bias ; optional bf16 copy
__global__ __launch_bounds__(256) void mlpB_kernel(
    const unsigned short* __restrict__ tin, const unsigned short* __restrict__ wm2t,
    const float* __restrict__ mb2, const float* __restrict__ bias,
    float* __restrict__ out, unsigned short* __restrict__ out_bf, int nNodes)
{
    int wid = blockIdx.x * 4 + (threadIdx.x >> 6);
    int lane = threadIdx.x & 63;
    int nbase = wid * 32;
    if (nbase >= nNodes) return;
    int r16 = lane & 15;
    int kg  = lane >> 4;

    int n0 = nbase + r16;      if (n0 >= nNodes) n0 = nNodes - 1;
    int n1 = nbase + 16 + r16; if (n1 >= nNodes) n1 = nNodes - 1;
    const unsigned short* a0p = tin + (long)n0 * ND + kg * 8;
    const unsigned short* a1p = tin + (long)n1 * ND + kg * 8;

    f32x4 acc[2][4];
#pragma unroll
    for (int m = 0; m < 2; ++m)
#pragma unroll
        for (int j = 0; j < 4; ++j) acc[m][j] = (f32x4){0.f, 0.f, 0.f, 0.f};

#pragma unroll
    for (int kk = 0; kk < 2; ++kk) {
        bf16x8 a0 = *(const bf16x8*)(a0p + kk * 32);
        bf16x8 a1 = *(const bf16x8*)(a1p + kk * 32);
#pragma unroll
        for (int j = 0; j < 4; ++j) {
            bf16x8 b = *(const bf16x8*)(wm2t + (long)(j * 16 + r16) * ND + kg * 8 + kk * 32);
            acc[0][j] = __builtin_amdgcn_mfma_f32_16x16x32_bf16(a0, b, acc[0][j], 0, 0, 0);
            acc[1][j] = __builtin_amdgcn_mfma_f32_16x16x32_bf16(a1, b, acc[1][j], 0, 0, 0);
        }
    }

#pragma unroll
    for (int m = 0; m < 2; ++m) {
#pragma unroll
        for (int reg = 0; reg < 4; ++reg) {
            int row = nbase + m * 16 + kg * 4 + reg;
            if (row < nNodes) {
#pragma unroll
                for (int j = 0; j < 4; ++j) {
                    int col = j * 16 + r16;
                    float v = acc[m][j][reg] + mb2[col] + bias[col];
                    out[(long)row * ND + col] = v;
                    if (out_bf != nullptr)
                        out_bf[(long)row * ND + col] = bf16_rne(v);
                }
            }
        }
    }
}

// ---------------------------------------------------------------- launch
extern "C" void kernel_launch(void* const* d_in, const int* in_sizes, int n_in,
                              void* d_out, int out_size, void* d_ws, size_t ws_size,
                              hipStream_t stream) {
    const float* x    = (const float*)d_in[0];
    const int* esrc   = (const int*)d_in[1];
    const int* edst   = (const int*)d_in[2];
    const int* etyp   = (const int*)d_in[3];

    const float* W1   = (const float*)d_in[4];
    const float* b1   = (const float*)d_in[5];
    const float* e1   = (const float*)d_in[6];
    const float* m1w1 = (const float*)d_in[7];
    const float* m1b1 = (const float*)d_in[8];
    const float* m1w2 = (const float*)d_in[9];
    const float* m1b2 = (const float*)d_in[10];

    const float* W2   = (const float*)d_in[11];
    const float* b2   = (const float*)d_in[12];
    const float* e2   = (const float*)d_in[13];
    const float* m2w1 = (const float*)d_in[14];
    const float* m2b1 = (const float*)d_in[15];
    const float* m2w2 = (const float*)d_in[16];
    const float* m2b2 = (const float*)d_in[17];

    int nNodes = in_sizes[0] / ND;   // 50000
    int nEdges = in_sizes[1];        // 1600000
    int S = NR * nNodes;             // 400000
    int nb = (S + SCAN_ELEMS - 1) / SCAN_ELEMS;

    // ---- workspace layout
    unsigned short* agbf = (unsigned short*)d_ws;                 // N*512 bf16
    float* msgs   = (float*)(agbf + (long)nNodes * 512);          // N*64 f32
    unsigned short* xhbf = (unsigned short*)(msgs + (long)nNodes * ND); // N*64 bf16
    unsigned short* tbuf = xhbf + (long)nNodes * ND;              // N*64 bf16
    unsigned short* wt1  = tbuf + (long)nNodes * ND;              // 64*512 bf16
    unsigned short* wt2  = wt1 + 64 * 512;
    unsigned short* wm11 = wt2 + 64 * 512;                        // 64*64 each
    unsigned short* wm12 = wm11 + 64 * 64;
    unsigned short* wm21 = wm12 + 64 * 64;
    unsigned short* wm22 = wm21 + 64 * 64;
    int* offsets  = (int*)(wm22 + 64 * 64);                       // S+1
    int* cnt_cur  = offsets + (S + 1);                            // S
    int* blockSums = cnt_cur + S;
    int* blockOffs = blockSums + 512;
    int* perm     = blockOffs + 512;                              // E
    float* h    = (float*)d_out;   // layer-1 fp32 h aliases d_out
    float* outp = (float*)d_out;

    int egrid = (nEdges + 255) / 256;
    int ggrid = 2048;
    int esgrid = ((nNodes + 31) / 32 + 3) / 4;
    int n8 = nNodes * ND / 8;
    int chunkSize = (nEdges + 255) / 256;    // 256 chunks
    int sliceSize = (nNodes + 7) / 8;        // 8 dst-slices

    // ---- build CSR once (R7 pipeline)
    zeroi_kernel<<<512, 256, 0, stream>>>(cnt_cur, S);
    hist_kernel<<<egrid, 256, 0, stream>>>(edst, etyp, cnt_cur, nEdges, nNodes);
    scan1_kernel<<<nb, SCAN_BLOCK, 0, stream>>>(cnt_cur, offsets, blockSums, S);
    scan2_kernel<<<1, 512, 0, stream>>>(blockSums, blockOffs, nb);
    scan3_kernel<<<nb, SCAN_BLOCK, 0, stream>>>(offsets, cnt_cur, blockOffs, S, nEdges);
    permute_kernel<<<256 * 8, 256, 0, stream>>>(esrc, edst, etyp, cnt_cur, perm,
                                                nEdges, nNodes, chunkSize, sliceSize);

    // ---- weight + x converts
    convw_kernel<<<128, 256, 0, stream>>>(W1, wt1);
    convw_kernel<<<128, 256, 0, stream>>>(W2, wt2);
    convm_kernel<<<16, 256, 0, stream>>>(m1w1, wm11);
    convm_kernel<<<16, 256, 0, stream>>>(m1w2, wm12);
    convm_kernel<<<16, 256, 0, stream>>>(m2w1, wm21);
    convm_kernel<<<16, 256, 0, stream>>>(m2w2, wm22);
    convx_kernel<<<(n8 + 255) / 256, 256, 0, stream>>>((const float4*)x, xhbf, n8);

    // ---- layer 1
    gather_kernel<<<ggrid, 256, 0, stream>>>(xhbf, offsets, perm, agbf, S, nNodes);
    einsum_kernel<<<esgrid, 256, 0, stream>>>(agbf, wt1, msgs, nNodes);
    mlpA_kernel<<<esgrid, 256, 0, stream>>>(x, msgs, e1, wm11, m1b1, tbuf, nNodes);
    mlpB_kernel<<<esgrid, 256, 0, stream>>>(tbuf, wm12, m1b2, b1, h, xhbf, nNodes);

    // ---- layer 2
    gather_kernel<<<ggrid, 256, 0, stream>>>(xhbf, offsets, perm, agbf, S, nNodes);
    einsum_kernel<<<esgrid, 256, 0, stream>>>(agbf, wt2, msgs, nNodes);
    mlpA_kernel<<<esgrid, 256, 0, stream>>>(h, msgs, e2, wm21, m2b1, tbuf, nNodes);
    mlpB_kernel<<<esgrid, 256, 0, stream>>>(tbuf, wm22, m2b2, b2, outp, nullptr, nNodes);
}